// Round 1
// 427.831 us; speedup vs baseline: 1.0277x; 1.0277x over previous
//
#include <hip/hip_runtime.h>
#include <cstdint>
#include <cstddef>

#define TLEN    50
#define BATCH   16
#define D_IN    512
#define SRC_LEN 200
#define VOCAB   20000
#define CVOCAB  20400

typedef __bf16 bf16x8 __attribute__((ext_vector_type(8)));
typedef float  f32x4  __attribute__((ext_vector_type(4)));

#define GEMM_BLOCKS 625                   // 32 vocab cols per block (2 waves x 16)
#define ZERO_BLOCKS 40
#define SCAN_BLOCKS (SRC_LEN * BATCH)     // 3200
#define NT 128                            // 2 waves per block

typedef __attribute__((address_space(3))) uint32_t lds_t;
typedef const __attribute__((address_space(1))) uint32_t glb_t;

// ---------------- kernel 0: prep -------------------------------------------
// blocks [0,200):   pc[800] = sigmoid(hidden . Wc + bc)
// blocks [200,400): hb = (bf16)hidden, linear (50,16,512). Converted ONCE here
// instead of 625x (once per GEMM block) as before — removes 64 v_cvt per
// thread per t-step from the GEMM staging path.
__global__ __launch_bounds__(256)
void prep_kernel(const float* __restrict__ hidden,
                 const float* __restrict__ Wc,
                 const float* __restrict__ bc,
                 float* __restrict__ pc,
                 __bf16* __restrict__ hb)
{
    const int bid = blockIdx.x;
    if (bid < 200) {
        const int row  = bid * 4 + (threadIdx.x >> 6);   // 0..799
        const int lane = threadIdx.x & 63;
        const float* h = hidden + (size_t)row * D_IN + lane * 8;
        float4 h0 = *(const float4*)(h);
        float4 h1 = *(const float4*)(h + 4);
        float4 w0 = *(const float4*)(Wc + lane * 8);
        float4 w1 = *(const float4*)(Wc + lane * 8 + 4);
        float s = h0.x*w0.x + h0.y*w0.y + h0.z*w0.z + h0.w*w0.w
                + h1.x*w1.x + h1.y*w1.y + h1.z*w1.z + h1.w*w1.w;
        #pragma unroll
        for (int o = 1; o < 64; o <<= 1) s += __shfl_xor(s, o);
        if (lane == 0) pc[row] = 1.0f / (1.0f + __expf(-(s + bc[0])));
    } else {
        // 200 blocks x 256 threads x 8 elems = 409600 = 50*16*512
        const int e = ((bid - 200) * 256 + threadIdx.x) * 8;
        float4 f0 = *(const float4*)(hidden + e);
        float4 f1 = *(const float4*)(hidden + e + 4);
        bf16x8 bf;
        bf[0] = (__bf16)f0.x; bf[1] = (__bf16)f0.y;
        bf[2] = (__bf16)f0.z; bf[3] = (__bf16)f0.w;
        bf[4] = (__bf16)f1.x; bf[5] = (__bf16)f1.y;
        bf[6] = (__bf16)f1.z; bf[7] = (__bf16)f1.w;
        *(bf16x8*)(hb + e) = bf;
    }
}

// ---------------- kernel 1: fused GEMM+softmax / tail-zero / src_map scan --
// Roles: [0,625) GEMM (long blocks, dispatched first), [625,665) zero,
// [665,3865) scan.
__global__ __launch_bounds__(NT)
void fused_main(const __bf16* __restrict__ hb,
                const float* __restrict__ src_map,
                const float* __restrict__ W,
                const float* __restrict__ pc,
                float* __restrict__ out,
                int* __restrict__ src_ids)
{
    const int bid = blockIdx.x;
    const int tid = threadIdx.x;

    if (bid < GEMM_BLOCKS) {
        // ---- GEMM (logits, bf16 MFMA) + softmax over batch + (1-pc) scale ----
        // b[v] bias is uniform along the softmax (batch) axis -> cancels; unused.
        //
        // A-staging via global_load_lds (direct-to-LDS, 16B/lane): LDS layout is
        // forced linear [16][512] bf16 (row stride 1024B = 16-way bank conflict
        // on ds_read_b128), so the bank fix is the pre-swizzled-SOURCE XOR
        // pattern: stage chunk j from global chunk j^((j>>6)&7); reader XORs
        // its byte offset with (l15&7)<<4. Involution verified: LDS[A] holds
        // element A^((row(A)&7)<<4), reader at E^((l15&7)<<4) gets element E.
        __shared__ __bf16 Alds[2][BATCH][D_IN];      // 2 x 16KB, linear, no pad

        const int lane = tid & 63;
        const int wv   = tid >> 6;            // 0..1
        const int l15  = lane & 15;
        const int q    = lane >> 4;
        const int colbase = bid * 32 + wv * 16;   // 625*32 == 20000 exactly

        // B fragments: 16 cols x 512 k -> 16 x bf16x8 = 64 VGPRs. Loaded ONCE
        // from HBM, then PINNED via empty asm so LLVM cannot sink the loads
        // into the t-loop (R2 pathology: VGPR=80 proved W was re-read 25x).
        bf16x8 bfrag[16];
        {
            const float* wrow = W + (size_t)(colbase + l15) * D_IN + q * 8;
            #pragma unroll
            for (int c = 0; c < 16; ++c) {
                float4 f0 = *(const float4*)(wrow + c * 32);
                float4 f1 = *(const float4*)(wrow + c * 32 + 4);
                bf16x8 bf;
                bf[0] = (__bf16)f0.x; bf[1] = (__bf16)f0.y;
                bf[2] = (__bf16)f0.z; bf[3] = (__bf16)f0.w;
                bf[4] = (__bf16)f1.x; bf[5] = (__bf16)f1.y;
                bf[6] = (__bf16)f1.z; bf[7] = (__bf16)f1.w;
                bfrag[c] = bf;
            }
            #pragma unroll
            for (int c = 0; c < 16; ++c) {
                f32x4 t = *(f32x4*)&bfrag[c];
                asm volatile("" : "+v"(t));
                bfrag[c] = *(bf16x8*)&t;
            }
        }

        // t-invariant per-thread source byte offsets within a 16KB tile.
        // chunk j = r*128 + tid (16B chunks); src chunk = j ^ ((j>>6)&7).
        int jsrc[8];
        #pragma unroll
        for (int r = 0; r < 8; ++r) {
            const int j = r * 128 + tid;
            jsrc[r] = (j ^ ((j >> 6) & 7)) << 4;
        }
        const char* hbb  = (const char*)hb;
        char* lbase = (char*)&Alds[0][0][0];

        // wave-uniform LDS dest (+lane*16 added by HW); per-lane global src.
        auto stage = [&](int t, int buf) {
            const char* gt = hbb + (size_t)t * (BATCH * D_IN * 2);
            char* lb = lbase + buf * 16384 + wv * 1024;
            #pragma unroll
            for (int r = 0; r < 8; ++r)
                __builtin_amdgcn_global_load_lds((glb_t*)(gt + jsrc[r]),
                                                 (lds_t*)(lb + r * 2048),
                                                 16, 0, 0);
        };

        stage(0, 0);

        const int xr = (l15 & 7) << 4;       // reader-side XOR (bits 4..6)

        for (int t = 0; t < TLEN; ++t) {
            __syncthreads();                 // drains vmcnt: staged(t) visible
            if (t + 1 < TLEN) stage(t + 1, (t + 1) & 1);

            const char* arow = lbase + (t & 1) * 16384 + l15 * 1024;
            f32x4 accA = {0.f, 0.f, 0.f, 0.f};
            f32x4 accB = {0.f, 0.f, 0.f, 0.f};
            #pragma unroll
            for (int c = 0; c < 16; c += 2) {
                // byte offset in row = k*2 = (c*32+q*8)*2 = c*64 + q*16
                bf16x8 a0 = *(const bf16x8*)(arow + ((c * 64      + q * 16) ^ xr));
                bf16x8 a1 = *(const bf16x8*)(arow + ((c * 64 + 64 + q * 16) ^ xr));
                accA = __builtin_amdgcn_mfma_f32_16x16x32_bf16(a0, bfrag[c],     accA, 0, 0, 0);
                accB = __builtin_amdgcn_mfma_f32_16x16x32_bf16(a1, bfrag[c + 1], accB, 0, 0, 0);
            }
            f32x4 acc = accA + accB;

            float4 pc4 = *(const float4*)(pc + t * 16 + q * 4);

            // softmax over batch (D rows), b==1 masked to prob 0
            float mx = -INFINITY;
            #pragma unroll
            for (int r = 0; r < 4; ++r)
                if (q * 4 + r != 1) mx = fmaxf(mx, acc[r]);
            mx = fmaxf(mx, __shfl_xor(mx, 16));
            mx = fmaxf(mx, __shfl_xor(mx, 32));
            float e[4], s = 0.f;
            #pragma unroll
            for (int r = 0; r < 4; ++r) {
                e[r] = (q * 4 + r == 1) ? 0.f : __expf(acc[r] - mx);
                s += e[r];
            }
            s += __shfl_xor(s, 16);
            s += __shfl_xor(s, 32);
            const float inv = 1.0f / s;
            const int v = colbase + l15;
            #pragma unroll
            for (int r = 0; r < 4; ++r) {
                const int b = q * 4 + r;
                out[(size_t)(t * BATCH + b) * CVOCAB + v] = e[r] * inv * (1.0f - pc4[r]);
            }
        }
    } else if (bid < GEMM_BLOCKS + ZERO_BLOCKS) {
        // ---- zero extended-vocab tail cols [20000,20400) of all 800 rows ----
        const int zb = bid - GEMM_BLOCKS;
        const float4 z = {0.f, 0.f, 0.f, 0.f};
        for (int i = tid; i < 2000; i += NT) {
            const int f = zb * 2000 + i;          // 0..79999 float4s, 100 per row
            const int r = f / 100;
            const int c = f % 100;
            *(float4*)(out + (size_t)r * CVOCAB + VOCAB + c * 4) = z;
        }
    } else {
        // ---- scan one one-hot src_map row (20400 fp32) -> index ----
        const int row = bid - GEMM_BLOCKS - ZERO_BLOCKS;   // (s*16+b)
        const float4* base = (const float4*)(src_map + (size_t)row * CVOCAB);
        int found = -1;
        for (int i0 = tid; i0 < 1275; i0 += NT) {
            float4 x0 = base[i0];
            float4 x1 = base[i0 + 1275];
            float4 x2 = base[i0 + 2550];
            float4 x3 = base[i0 + 3825];
            #pragma unroll
            for (int seg = 0; seg < 4; ++seg) {
                float4 x = seg == 0 ? x0 : seg == 1 ? x1 : seg == 2 ? x2 : x3;
                const int e0 = (i0 + seg * 1275) * 4;
                if (x.x > 0.5f) found = e0;
                if (x.y > 0.5f) found = e0 + 1;
                if (x.z > 0.5f) found = e0 + 2;
                if (x.w > 0.5f) found = e0 + 3;
            }
        }
        if (found >= 0) src_ids[row] = found;     // exactly one finder per row
    }
}

// ---------------- kernel 2: scatter copy-probs ------------------------------
// r=t*16+b; reference's split/stack/transpose sends copy_prob[t,b,:] to
// output row (t'=r%50, b'=r/50). atomicAdd onto already-written out_prob.
// Dense grid: w = p*200+si over 160000 items (no idle threads; attn read
// perfectly coalesced).
__global__ __launch_bounds__(256)
void scatter_copy(const float* __restrict__ attn,
                  const float* __restrict__ pc,
                  const int* __restrict__ src_ids,
                  float* __restrict__ out)
{
    const int w  = blockIdx.x * 256 + threadIdx.x;   // 0..159999
    const int p  = w / SRC_LEN;                       // 0..799
    const int si = w - p * SRC_LEN;                   // 0..199
    const int b  = p & 15;
    const size_t obase = (size_t)((p % TLEN) * BATCH + (p / TLEN)) * CVOCAB;
    const int id = src_ids[si * BATCH + b];
    const float val = attn[w] * pc[p];
    if ((unsigned)id < (unsigned)CVOCAB)
        atomicAdd(out + obase + id, val);
}

extern "C" void kernel_launch(void* const* d_in, const int* in_sizes, int n_in,
                              void* d_out, int out_size, void* d_ws, size_t ws_size,
                              hipStream_t stream)
{
    const float* hidden  = (const float*)d_in[0];  // (50,16,512)
    const float* attn    = (const float*)d_in[1];  // (50,16,200)
    const float* src_map = (const float*)d_in[2];  // (200,16,20400) one-hot
    const float* W       = (const float*)d_in[3];  // (20000,512)
    // d_in[4] = b (20000): cancels in softmax over batch -> unused
    const float* Wc      = (const float*)d_in[5];  // (1,512)
    const float* bc      = (const float*)d_in[6];  // (1,)
    float* out   = (float*)d_out;                  // (50,16,20400)

    // workspace layout: hb (bf16 hidden, 819200 B) | src_ids (12800 B) | pc (3200 B)
    __bf16* hb   = (__bf16*)d_ws;
    int* src_ids = (int*)((char*)d_ws + 819200);
    float* pc    = (float*)((char*)d_ws + 819200 + 12800);

    prep_kernel<<<dim3(400), dim3(256), 0, stream>>>(hidden, Wc, bc, pc, hb);
    fused_main<<<dim3(GEMM_BLOCKS + ZERO_BLOCKS + SCAN_BLOCKS), dim3(NT), 0, stream>>>(
        hb, src_map, W, pc, out, src_ids);
    scatter_copy<<<dim3(625), dim3(256), 0, stream>>>(attn, pc, src_ids, out);
}